// Round 2
// baseline (237.511 us; speedup 1.0000x reference)
//
#include <hip/hip_runtime.h>
#include <math.h>

#define N_NODES 20000
#define N_EDGES 320000
#define F_IN 40
#define T_TOW 5
#define EMB 40
#define NPB_PRE 16      // nodes per block in projection kernel -> 1250 blocks
#define NBLK_MIX 313    // ceil(20000/64) for k_head
#define NPB_PM 16       // nodes per block in fused post+mix -> 1250 blocks
#define NBLK_PM 1250
#define PLANE (T_TOW * N_NODES * 40)   // halfs per stat plane (8 MB)
#define ECHUNK 16       // edge-loop software-pipeline depth
#define STRIDE 64       // fixed CSR bucket stride (Poisson(16) tail @64 ~ 1e-20)

typedef __attribute__((ext_vector_type(8))) _Float16 half8;
typedef __attribute__((ext_vector_type(2))) _Float16 half2_t;

// workspace byte offsets (all 64B-aligned)
#define WS_STATS   0          // S1[40], S2[40] float (written by k_stats)
#define WS_CURSOR  320        // int[N]  init to 64n by k_pre, bumped by k_scatter
#define WS_SSRC    80384      // int[N*64] fixed-stride edge buckets (5.12 MB)
#define WS_MS      5200384    // half[N*200] src-projection
#define WS_MD      13200384   // half[N*200] dst-projection (+bias)
#define WS_AGG     21200384   // half[4][5][N][40] stat-major agg (32 MB)
#define WS_XPOST   53200384   // float[5][N][8]  x-part of post (+b_post)
#define WS_H0T     69200384   // float[40][N]    h0 transposed
#define WS_PART    72400384   // float[NBLK_PM*80] per-block stat partials (400 KB)

// ---------------- K_pre: per-node projections + x-part of post + cursor init --
__global__ __launch_bounds__(256) void k_pre(const float* __restrict__ x,
                                             const float* __restrict__ W_pre,
                                             const float* __restrict__ b_pre,
                                             const float* __restrict__ W_post,
                                             const float* __restrict__ b_post,
                                             _Float16* __restrict__ mS,
                                             _Float16* __restrict__ mD,
                                             float* __restrict__ xpostT,
                                             int* __restrict__ cursor) {
  const int tid = threadIdx.x;
  const int n0 = blockIdx.x * NPB_PRE;
  if (tid < NPB_PRE) cursor[n0 + tid] = (n0 + tid) * STRIDE;  // bucket-CSR init
  const bool statlane = tid < 200;
  const int q = tid - 200;
  const bool xplane = (q >= 0 && q < 40);
  const int tc = statlane ? tid : 199;
  const int t = tc / 40, g = tc - t * 40;
  const int t2 = xplane ? q / 8 : 0, g2 = xplane ? q - (q / 8) * 8 : 0;
  float wA[40], wB[40];
  const float* Wt = W_pre + t * 3200;
#pragma unroll
  for (int j = 0; j < 40; ++j) {
    wA[j] = statlane ? Wt[j * 40 + g] : W_post[t2 * 4160 + j * 8 + g2];
    wB[j] = statlane ? Wt[(40 + j) * 40 + g] : 0.f;
  }
  const float bias = statlane ? b_pre[t * 40 + g] : b_post[t2 * 8 + g2];
  for (int ni = 0; ni < NPB_PRE; ++ni) {
    const int n = n0 + ni;
    const float* xr = x + n * F_IN;
    float aA = bias, aB = 0.f;
#pragma unroll
    for (int j = 0; j < 40; j += 4) {
      const float4 xv = *(const float4*)(xr + j);
      aA += xv.x * wA[j] + xv.y * wA[j + 1] + xv.z * wA[j + 2] + xv.w * wA[j + 3];
      aB += xv.x * wB[j] + xv.y * wB[j + 1] + xv.z * wB[j + 2] + xv.w * wB[j + 3];
    }
    if (statlane) {
      mD[n * 200 + tc] = (_Float16)aA;
      mS[n * 200 + tc] = (_Float16)aB;
    } else if (xplane) {
      xpostT[t2 * (N_NODES * 8) + n * 8 + g2] = aA;
    }
  }
}

// ---------------- K3: scatter edges into fixed-stride buckets ----------------
__global__ __launch_bounds__(256) void k_scatter(const int* __restrict__ src,
                                                 const int* __restrict__ dst,
                                                 int* __restrict__ cursor,
                                                 int* __restrict__ ssrc) {
  int i = blockIdx.x * 256 + threadIdx.x;
  if (i < N_EDGES) {
    int d = dst[i];
    int pos = atomicAdd(&cursor[d], 1);
    ssrc[pos] = src[i];
  }
}

// ---------------- K4: edge loop; one wave per node, packed-fp16 math ----------
__global__ __launch_bounds__(256) void k_edge(const _Float16* __restrict__ mS,
                                              const _Float16* __restrict__ mD,
                                              const int* __restrict__ cursor,
                                              const int* __restrict__ ssrc,
                                              _Float16* __restrict__ aggS) {
  const int lane = threadIdx.x & 63;
  const int wv = threadIdx.x >> 6;
  const int n = blockIdx.x * 4 + wv;             // one wave per node
  const int r0 = n * STRIDE;                     // scalar
  const int r1 = __builtin_amdgcn_readfirstlane(cursor[n]);
  const int cnt = r1 - r0;
  const int cpa = lane;                          // cols 2l, 2l+1
  const bool bact = lane < 36;                   // cp 64..99 -> cols 128..199
  const int cpb = bact ? 64 + lane : 99;
  const half2_t mda = ((const half2_t*)(mD + n * 200))[cpa];
  const half2_t mdb = ((const half2_t*)(mD + n * 200))[cpb];

  const _Float16 HINF = (_Float16)65504.f;
  half2_t suma = {0, 0}, ssqa = {0, 0}, sumb = {0, 0}, ssqb = {0, 0};
  half2_t mna = {HINF, HINF}, mxa = {-HINF, -HINF};
  half2_t mnb = {HINF, HINF}, mxb = {-HINF, -HINF};
  half2_t va = {0, 0}, vb = {0, 0};

  if (cnt > 0) {
    for (int p = r0; p < r1; p += ECHUNK) {
      half2_t ha[ECHUNK], hb[ECHUNK];
#pragma unroll
      for (int i = 0; i < ECHUNK; ++i) {
        const int qe = (p + i < r1) ? (p + i) : (r1 - 1);   // s_cselect
        const int s = __builtin_amdgcn_readfirstlane(ssrc[qe]);
        const half2_t* row = (const half2_t*)(mS + s * 200);
        ha[i] = row[cpa];
        hb[i] = row[cpb];
      }
#pragma unroll
      for (int i = 0; i < ECHUNK; ++i) {
        suma += ha[i];
        ssqa += ha[i] * ha[i];
        mna = __builtin_elementwise_min(mna, ha[i]);
        mxa = __builtin_elementwise_max(mxa, ha[i]);
        sumb += hb[i];
        ssqb += hb[i] * hb[i];
        mnb = __builtin_elementwise_min(mnb, hb[i]);
        mxb = __builtin_elementwise_max(mxb, hb[i]);
      }
      va = ha[ECHUNK - 1];
      vb = hb[ECHUNK - 1];
    }
  }

  const int padded = ((cnt + ECHUNK - 1) / ECHUNK) * ECHUNK;
  const float d = (float)(padded - cnt);
  const float inv = (cnt > 0) ? 1.f / (float)cnt : 0.f;
#pragma unroll
  for (int set = 0; set < 2; ++set) {
    if (set == 1 && !bact) break;
    const int cp = set == 0 ? cpa : cpb;
    const half2_t sum2 = set == 0 ? suma : sumb;
    const half2_t ssq2 = set == 0 ? ssqa : ssqb;
    const half2_t mn2 = set == 0 ? mna : mnb;
    const half2_t mx2 = set == 0 ? mxa : mxb;
    const half2_t vl2 = set == 0 ? va : vb;
    const half2_t md2 = set == 0 ? mda : mdb;
    half2_t omean, omn, omx, osd;
#pragma unroll
    for (int j = 0; j < 2; ++j) {
      float mean, mnf, mxf, sd;
      if (cnt > 0) {
        const float vl = (float)vl2[j];
        const float sf = (float)sum2[j] - d * vl;
        const float qf = (float)ssq2[j] - d * vl * vl;
        const float msm = sf * inv;
        const float var = qf * inv - msm * msm;
        sd = sqrtf(fmaxf(var, 0.f) + 1e-5f);
        const float mdf = (float)md2[j];
        mean = mdf + msm;
        mnf = mdf + (float)mn2[j];
        mxf = mdf + (float)mx2[j];
      } else {
        mean = 0.f; mnf = 0.f; mxf = 0.f; sd = sqrtf(1e-5f);
      }
      omean[j] = (_Float16)mean;
      omn[j] = (_Float16)mnf;
      omx[j] = (_Float16)mxf;
      osd[j] = (_Float16)sd;
    }
    const int t = cp / 20, g = 2 * (cp - t * 20);
    half2_t* a = (half2_t*)(aggS + (t * N_NODES + n) * 40 + g);
    a[0] = omean;
    *(half2_t*)((_Float16*)a + PLANE) = omn;
    *(half2_t*)((_Float16*)a + 2 * PLANE) = omx;
    *(half2_t*)((_Float16*)a + 3 * PLANE) = osd;
  }
}

// ---------------- K5: fused post-MLP + W_lin mix, high-occupancy --------------
// 1250 blocks x 320 threads, 16 nodes/block. Phase A: wave = tower t, lane =
// (stat s = l>>4, node ni = l&15); per-thread 40->8 x3 dot; stat-sum via
// shfl_xor(16/32); lanes s==0 add xpost and write sP[16][41]. Phase B: wave =
// col-group, lane = (node nb = l>>2, colpair cq = l&3); 40x2 fma; block stat
// partials via shfl_xor(4..32) -> partial[1250][80].
__global__ __launch_bounds__(320) void k_postmix(const _Float16* __restrict__ aggS,
                                                 const int* __restrict__ cursor,
                                                 const float* __restrict__ W_post,
                                                 const float* __restrict__ avg_dl,
                                                 const float* __restrict__ xpostT,
                                                 const float* __restrict__ W_lin,
                                                 const float* __restrict__ b_lin,
                                                 float* __restrict__ h0T,
                                                 float* __restrict__ partial) {
  __shared__ float sP[16 * 41];
  const int tid = threadIdx.x;
  const int t = tid >> 6;            // tower (wave-uniform)
  const int l = tid & 63;
  const int s = l >> 4;              // stat
  const int ni = l & 15;             // node within block
  const int n0 = blockIdx.x * NPB_PM;
  const int n = n0 + ni;

  // per-node degree scalers
  const int cnt = cursor[n] - n * STRIDE;
  const float degf = fmaxf((float)cnt, 1.f);
  const float logd = logf(degf + 1.f);
  const float avg = avg_dl[0];
  const float s1v = logd / avg, s2v = avg / logd;

  // ---- Phase A: one (n, s, t) 40->8 x {A,B,C} dot product per thread
  half8 cur[5];
  {
    const half8* ar = (const half8*)(aggS + s * PLANE + ((size_t)t * N_NODES + n) * 40);
#pragma unroll
    for (int q2 = 0; q2 < 5; ++q2) cur[q2] = ar[q2];
  }
  const float* Wt = W_post + t * 4160 + (40 + s * 40) * 8;
  float A[8], B[8], C[8];
#pragma unroll
  for (int g = 0; g < 8; ++g) { A[g] = 0.f; B[g] = 0.f; C[g] = 0.f; }
#pragma unroll
  for (int f = 0; f < 40; ++f) {
    const float val = (float)cur[f >> 3][f & 7];
    const float* wrow = Wt + f * 8;
#pragma unroll
    for (int g = 0; g < 8; ++g) {
      A[g] = fmaf(val, wrow[g], A[g]);
      B[g] = fmaf(val, wrow[1280 + g], B[g]);
      C[g] = fmaf(val, wrow[2560 + g], C[g]);
    }
  }
  float v[8];
#pragma unroll
  for (int g = 0; g < 8; ++g) {
    v[g] = A[g] + s1v * B[g] + s2v * C[g];
    v[g] += __shfl_xor(v[g], 16, 64);      // sum stat pairs
    v[g] += __shfl_xor(v[g], 32, 64);      // sum all 4 stats
  }
  if (s == 0) {
    const float* xp = xpostT + t * (N_NODES * 8) + n * 8;
#pragma unroll
    for (int g = 0; g < 8; ++g) sP[ni * 41 + t * 8 + g] = v[g] + xp[g];
  }
  __syncthreads();

  // ---- Phase B: W_lin mix (40x40) + per-block stat partials
  const int cq = l & 3;
  const int nb = l >> 2;             // node for phase B
  const int nB = n0 + nb;
  const int cc = t * 8 + cq * 2;
  float a0 = b_lin[cc], a1 = b_lin[cc + 1];
  for (int k = 0; k < 40; ++k) {
    const float p = sP[nb * 41 + k];
    const float2 w = *(const float2*)(W_lin + k * EMB + cc);
    a0 = fmaf(p, w.x, a0);
    a1 = fmaf(p, w.y, a1);
  }
  h0T[cc * N_NODES + nB] = a0;
  h0T[(cc + 1) * N_NODES + nB] = a1;
  float q0 = a0 * a0, q1 = a1 * a1;
#pragma unroll
  for (int m = 4; m <= 32; m <<= 1) {
    a0 += __shfl_xor(a0, m, 64);
    a1 += __shfl_xor(a1, m, 64);
    q0 += __shfl_xor(q0, m, 64);
    q1 += __shfl_xor(q1, m, 64);
  }
  if (nb == 0) {
    float* pb = partial + blockIdx.x * 80;
    pb[cc] = a0;
    pb[cc + 1] = a1;
    pb[40 + cc] = q0;
    pb[40 + cc + 1] = q1;
  }
}

// ---------------- K6: reduce partial[1250][80] -> S1[40], S2[40] --------------
__global__ __launch_bounds__(256) void k_stats(const float* __restrict__ partial,
                                               float* __restrict__ S1,
                                               float* __restrict__ S2) {
  const int col = blockIdx.x;        // 0..79
  const int tid = threadIdx.x;
  __shared__ float red[4];
  float s = 0.f;
  for (int b = tid; b < NBLK_PM; b += 256) s += partial[b * 80 + col];
#pragma unroll
  for (int m = 32; m >= 1; m >>= 1) s += __shfl_xor(s, m, 64);
  if ((tid & 63) == 0) red[tid >> 6] = s;
  __syncthreads();
  if (tid == 0) {
    const float tot = (red[0] + red[1]) + (red[2] + red[3]);
    if (col < 40) S1[col] = tot;
    else S2[col - 40] = tot;
  }
}

// ---------------- K7: head; GN + MLP ----------------
__global__ __launch_bounds__(256) void k_head(const float* __restrict__ S1,
                                              const float* __restrict__ S2,
                                              const float* __restrict__ h0T,
                                              const float* __restrict__ gn_w,
                                              const float* __restrict__ gn_b,
                                              const float* __restrict__ gn_ms,
                                              const float* __restrict__ W1,
                                              const float* __restrict__ b1,
                                              const float* __restrict__ W2,
                                              const float* __restrict__ b2,
                                              float* __restrict__ out) {
  __shared__ float sV[64 * 41];
  __shared__ float sH[64 * 41];
  const int tid = threadIdx.x;
  const int n0 = blockIdx.x * 64;
  const float invN = 1.f / (float)N_NODES;
  for (int i = 0; i < 10; ++i) {
    const int idx = tid + i * 256;
    const int e = idx >> 6, r = idx & 63;
    const int nn0 = n0 + r;
    const int nn = (nn0 < N_NODES) ? nn0 : 0;
    const float M = S1[e] * invN;
    const float ms = gn_ms[e];
    const float var = S2[e] * invN - ms * (2.f - ms) * M * M;
    const float sc = gn_w[e] / sqrtf(var + 1e-5f);
    const float he = h0T[e * N_NODES + nn];       // coalesced (lane = node)
    sV[r * 41 + e] = fmaxf((he - ms * M) * sc + gn_b[e], 0.f);
  }
  __syncthreads();
  const int wv = tid >> 6, lane = tid & 63;
  const int c0 = wv * 10;
  float acc[10];
#pragma unroll
  for (int j = 0; j < 10; ++j) acc[j] = b1[c0 + j];
  for (int k = 0; k < 40; ++k) {
    const float p = sV[lane * 41 + k];
    const float* w = W1 + k * EMB + c0;           // wave-uniform -> scalar
#pragma unroll
    for (int j = 0; j < 10; ++j) acc[j] = fmaf(p, w[j], acc[j]);
  }
#pragma unroll
  for (int j = 0; j < 10; ++j) sH[lane * 41 + c0 + j] = fmaxf(acc[j], 0.f);
  __syncthreads();
  if (tid < 64) {
    const int n = n0 + tid;
    if (n < N_NODES) {
      float o0 = b2[0], o1 = b2[1];
      const float* hr = sH + tid * 41;
#pragma unroll
      for (int k = 0; k < 40; ++k) {
        const float r = hr[k];
        o0 = fmaf(r, W2[k * 2], o0);
        o1 = fmaf(r, W2[k * 2 + 1], o1);
      }
      out[n * 2] = o0;
      out[n * 2 + 1] = o1;
    }
  }
}

extern "C" void kernel_launch(void* const* d_in, const int* in_sizes, int n_in,
                              void* d_out, int out_size, void* d_ws, size_t ws_size,
                              hipStream_t stream) {
  const float* x      = (const float*)d_in[0];
  const int*   ei     = (const int*)d_in[1];
  const float* W_pre  = (const float*)d_in[2];
  const float* b_pre  = (const float*)d_in[3];
  const float* W_post = (const float*)d_in[4];
  const float* b_post = (const float*)d_in[5];
  const float* W_lin  = (const float*)d_in[6];
  const float* b_lin  = (const float*)d_in[7];
  const float* gn_w   = (const float*)d_in[8];
  const float* gn_b   = (const float*)d_in[9];
  const float* gn_ms  = (const float*)d_in[10];
  const float* W1     = (const float*)d_in[11];
  const float* b1     = (const float*)d_in[12];
  const float* W2     = (const float*)d_in[13];
  const float* b2     = (const float*)d_in[14];
  const float* avg_dl = (const float*)d_in[15];
  float* out = (float*)d_out;

  char* ws = (char*)d_ws;
  float* S1   = (float*)(ws + WS_STATS);
  float* S2   = S1 + 40;
  int* cursor = (int*)(ws + WS_CURSOR);
  int* ssrc   = (int*)(ws + WS_SSRC);
  _Float16* mS   = (_Float16*)(ws + WS_MS);
  _Float16* mD   = (_Float16*)(ws + WS_MD);
  _Float16* aggS = (_Float16*)(ws + WS_AGG);
  float* xpostT  = (float*)(ws + WS_XPOST);
  float* h0T     = (float*)(ws + WS_H0T);
  float* part    = (float*)(ws + WS_PART);
  const int* e_src = ei;
  const int* e_dst = ei + N_EDGES;

  k_pre<<<N_NODES / NPB_PRE, 256, 0, stream>>>(x, W_pre, b_pre, W_post, b_post,
                                               mS, mD, xpostT, cursor);
  k_scatter<<<(N_EDGES + 255) / 256, 256, 0, stream>>>(e_src, e_dst, cursor, ssrc);
  k_edge<<<N_NODES / 4, 256, 0, stream>>>(mS, mD, cursor, ssrc, aggS);
  k_postmix<<<NBLK_PM, 320, 0, stream>>>(aggS, cursor, W_post, avg_dl,
                                         xpostT, W_lin, b_lin, h0T, part);
  k_stats<<<80, 256, 0, stream>>>(part, S1, S2);
  k_head<<<NBLK_MIX, 256, 0, stream>>>(S1, S2, h0T, gn_w, gn_b, gn_ms,
                                       W1, b1, W2, b2, out);
}

// Round 3
// 223.129 us; speedup vs baseline: 1.0645x; 1.0645x over previous
//
#include <hip/hip_runtime.h>
#include <math.h>

#define N_NODES 20000
#define N_EDGES 320000
#define F_IN 40
#define T_TOW 5
#define EMB 40
#define NPB_PRE 16      // nodes per block in projection kernel -> 1250 blocks
#define NBLK_MIX 313    // ceil(20000/64) for k_head
#define NPB_PM 32       // nodes per block in fused post+mix -> 625 blocks (exact)
#define NBLK_PM 625
#define PLANE (T_TOW * N_NODES * 40)   // halfs per stat plane (8 MB)
#define ECHUNK 16       // edge-loop software-pipeline depth
#define STRIDE 64       // fixed CSR bucket stride (Poisson(16) tail @64 ~ 1e-20)

typedef __attribute__((ext_vector_type(8))) _Float16 half8;
typedef __attribute__((ext_vector_type(2))) _Float16 half2_t;

// workspace byte offsets (all 64B-aligned)
#define WS_STATS   0          // S1[40], S2[40] float (written by k_stats)
#define WS_CURSOR  320        // int[N]  init to 64n by k_pre, bumped by k_scatter
#define WS_SSRC    80384      // int[N*64] fixed-stride edge buckets (5.12 MB)
#define WS_MS      5200384    // half[N*200] src-projection
#define WS_MD      13200384   // half[N*200] dst-projection (+bias)
#define WS_AGG     21200384   // half[4][5][N][40] stat-major agg (32 MB)
#define WS_XPOST   53200384   // float[5][N][8]  x-part of post (+b_post)
#define WS_H0T     69200384   // float[40][N]    h0 transposed
#define WS_PART    72400384   // float[NBLK_PM*80] per-block stat partials (200 KB)

// ---------------- K_pre: per-node projections + x-part of post + cursor init --
__global__ __launch_bounds__(256) void k_pre(const float* __restrict__ x,
                                             const float* __restrict__ W_pre,
                                             const float* __restrict__ b_pre,
                                             const float* __restrict__ W_post,
                                             const float* __restrict__ b_post,
                                             _Float16* __restrict__ mS,
                                             _Float16* __restrict__ mD,
                                             float* __restrict__ xpostT,
                                             int* __restrict__ cursor) {
  const int tid = threadIdx.x;
  const int n0 = blockIdx.x * NPB_PRE;
  if (tid < NPB_PRE) cursor[n0 + tid] = (n0 + tid) * STRIDE;  // bucket-CSR init
  const bool statlane = tid < 200;
  const int q = tid - 200;
  const bool xplane = (q >= 0 && q < 40);
  const int tc = statlane ? tid : 199;
  const int t = tc / 40, g = tc - t * 40;
  const int t2 = xplane ? q / 8 : 0, g2 = xplane ? q - (q / 8) * 8 : 0;
  float wA[40], wB[40];
  const float* Wt = W_pre + t * 3200;
#pragma unroll
  for (int j = 0; j < 40; ++j) {
    wA[j] = statlane ? Wt[j * 40 + g] : W_post[t2 * 4160 + j * 8 + g2];
    wB[j] = statlane ? Wt[(40 + j) * 40 + g] : 0.f;
  }
  const float bias = statlane ? b_pre[t * 40 + g] : b_post[t2 * 8 + g2];
  for (int ni = 0; ni < NPB_PRE; ++ni) {
    const int n = n0 + ni;
    const float* xr = x + n * F_IN;
    float aA = bias, aB = 0.f;
#pragma unroll
    for (int j = 0; j < 40; j += 4) {
      const float4 xv = *(const float4*)(xr + j);
      aA += xv.x * wA[j] + xv.y * wA[j + 1] + xv.z * wA[j + 2] + xv.w * wA[j + 3];
      aB += xv.x * wB[j] + xv.y * wB[j + 1] + xv.z * wB[j + 2] + xv.w * wB[j + 3];
    }
    if (statlane) {
      mD[n * 200 + tc] = (_Float16)aA;
      mS[n * 200 + tc] = (_Float16)aB;
    } else if (xplane) {
      xpostT[t2 * (N_NODES * 8) + n * 8 + g2] = aA;
    }
  }
}

// ---------------- K3: scatter edges into fixed-stride buckets ----------------
__global__ __launch_bounds__(256) void k_scatter(const int* __restrict__ src,
                                                 const int* __restrict__ dst,
                                                 int* __restrict__ cursor,
                                                 int* __restrict__ ssrc) {
  int i = blockIdx.x * 256 + threadIdx.x;
  if (i < N_EDGES) {
    int d = dst[i];
    int pos = atomicAdd(&cursor[d], 1);
    ssrc[pos] = src[i];
  }
}

// ---------------- K4: edge loop; one wave per node, packed-fp16 math ----------
__global__ __launch_bounds__(256) void k_edge(const _Float16* __restrict__ mS,
                                              const _Float16* __restrict__ mD,
                                              const int* __restrict__ cursor,
                                              const int* __restrict__ ssrc,
                                              _Float16* __restrict__ aggS) {
  const int lane = threadIdx.x & 63;
  const int wv = threadIdx.x >> 6;
  const int n = blockIdx.x * 4 + wv;             // one wave per node
  const int r0 = n * STRIDE;                     // scalar
  const int r1 = __builtin_amdgcn_readfirstlane(cursor[n]);
  const int cnt = r1 - r0;
  const int cpa = lane;                          // cols 2l, 2l+1
  const bool bact = lane < 36;                   // cp 64..99 -> cols 128..199
  const int cpb = bact ? 64 + lane : 99;
  const half2_t mda = ((const half2_t*)(mD + n * 200))[cpa];
  const half2_t mdb = ((const half2_t*)(mD + n * 200))[cpb];

  const _Float16 HINF = (_Float16)65504.f;
  half2_t suma = {0, 0}, ssqa = {0, 0}, sumb = {0, 0}, ssqb = {0, 0};
  half2_t mna = {HINF, HINF}, mxa = {-HINF, -HINF};
  half2_t mnb = {HINF, HINF}, mxb = {-HINF, -HINF};
  half2_t va = {0, 0}, vb = {0, 0};

  if (cnt > 0) {
    for (int p = r0; p < r1; p += ECHUNK) {
      half2_t ha[ECHUNK], hb[ECHUNK];
#pragma unroll
      for (int i = 0; i < ECHUNK; ++i) {
        const int qe = (p + i < r1) ? (p + i) : (r1 - 1);   // s_cselect
        const int s = __builtin_amdgcn_readfirstlane(ssrc[qe]);
        const half2_t* row = (const half2_t*)(mS + s * 200);
        ha[i] = row[cpa];
        hb[i] = row[cpb];
      }
#pragma unroll
      for (int i = 0; i < ECHUNK; ++i) {
        suma += ha[i];
        ssqa += ha[i] * ha[i];
        mna = __builtin_elementwise_min(mna, ha[i]);
        mxa = __builtin_elementwise_max(mxa, ha[i]);
        sumb += hb[i];
        ssqb += hb[i] * hb[i];
        mnb = __builtin_elementwise_min(mnb, hb[i]);
        mxb = __builtin_elementwise_max(mxb, hb[i]);
      }
      va = ha[ECHUNK - 1];
      vb = hb[ECHUNK - 1];
    }
  }

  const int padded = ((cnt + ECHUNK - 1) / ECHUNK) * ECHUNK;
  const float d = (float)(padded - cnt);
  const float inv = (cnt > 0) ? 1.f / (float)cnt : 0.f;
#pragma unroll
  for (int set = 0; set < 2; ++set) {
    if (set == 1 && !bact) break;
    const int cp = set == 0 ? cpa : cpb;
    const half2_t sum2 = set == 0 ? suma : sumb;
    const half2_t ssq2 = set == 0 ? ssqa : ssqb;
    const half2_t mn2 = set == 0 ? mna : mnb;
    const half2_t mx2 = set == 0 ? mxa : mxb;
    const half2_t vl2 = set == 0 ? va : vb;
    const half2_t md2 = set == 0 ? mda : mdb;
    half2_t omean, omn, omx, osd;
#pragma unroll
    for (int j = 0; j < 2; ++j) {
      float mean, mnf, mxf, sd;
      if (cnt > 0) {
        const float vl = (float)vl2[j];
        const float sf = (float)sum2[j] - d * vl;
        const float qf = (float)ssq2[j] - d * vl * vl;
        const float msm = sf * inv;
        const float var = qf * inv - msm * msm;
        sd = sqrtf(fmaxf(var, 0.f) + 1e-5f);
        const float mdf = (float)md2[j];
        mean = mdf + msm;
        mnf = mdf + (float)mn2[j];
        mxf = mdf + (float)mx2[j];
      } else {
        mean = 0.f; mnf = 0.f; mxf = 0.f; sd = sqrtf(1e-5f);
      }
      omean[j] = (_Float16)mean;
      omn[j] = (_Float16)mnf;
      omx[j] = (_Float16)mxf;
      osd[j] = (_Float16)sd;
    }
    const int t = cp / 20, g = 2 * (cp - t * 20);
    half2_t* a = (half2_t*)(aggS + (t * N_NODES + n) * 40 + g);
    a[0] = omean;
    *(half2_t*)((_Float16*)a + PLANE) = omn;
    *(half2_t*)((_Float16*)a + 2 * PLANE) = omx;
    *(half2_t*)((_Float16*)a + 3 * PLANE) = osd;
  }
}

// ---------------- K5: fused post-MLP + W_lin mix, 2 nodes/thread --------------
// 625 blocks x 320 threads, 32 nodes/block. Phase A: wave = tower t, lane =
// (stat s = l>>4, ni = l&15); thread handles nodes (n0+ni, n0+ni+16) -> 10
// independent half8 loads in flight (4x MLP of prior version). Per-node
// combined weight (w0 + s1*w1 + s2*w2) -> 16 accumulators. Stat-sum via
// shfl_xor(16/32); s==0 lanes add xpost, write sP[32][41]. Phase B: 2 nodes x
// col-pair per thread; partials via shfl_xor(4..32) -> partial[625][80].
__global__ __launch_bounds__(320) void k_postmix(const _Float16* __restrict__ aggS,
                                                 const int* __restrict__ cursor,
                                                 const float* __restrict__ W_post,
                                                 const float* __restrict__ avg_dl,
                                                 const float* __restrict__ xpostT,
                                                 const float* __restrict__ W_lin,
                                                 const float* __restrict__ b_lin,
                                                 float* __restrict__ h0T,
                                                 float* __restrict__ partial) {
  __shared__ float sP[32 * 41];
  const int tid = threadIdx.x;
  const int t = tid >> 6;            // tower (wave-uniform)
  const int l = tid & 63;
  const int s = l >> 4;              // stat
  const int ni = l & 15;             // node A within block
  const int n0 = blockIdx.x * NPB_PM;
  const int nA = n0 + ni;
  const int nB = nA + 16;

  // per-node degree scalers
  const float avg = avg_dl[0];
  const int cntA = cursor[nA] - nA * STRIDE;
  const int cntB = cursor[nB] - nB * STRIDE;
  const float ldA = logf(fmaxf((float)cntA, 1.f) + 1.f);
  const float ldB = logf(fmaxf((float)cntB, 1.f) + 1.f);
  const float s1A = ldA / avg, s2A = avg / ldA;
  const float s1B = ldB / avg, s2B = avg / ldB;

  // ---- Phase A: issue all 10 aggS loads up front (320 B in flight/thread)
  half8 curA[5], curB[5];
  {
    const half8* arA = (const half8*)(aggS + (size_t)s * PLANE +
                                      ((size_t)t * N_NODES + nA) * 40);
    const half8* arB = arA + 80;     // +16 nodes * 40 halfs
#pragma unroll
    for (int q2 = 0; q2 < 5; ++q2) curA[q2] = arA[q2];
#pragma unroll
    for (int q2 = 0; q2 < 5; ++q2) curB[q2] = arB[q2];
  }
  const float* Wt = W_post + t * 4160 + (40 + s * 40) * 8;
  float accA[8], accB[8];
#pragma unroll
  for (int g = 0; g < 8; ++g) { accA[g] = 0.f; accB[g] = 0.f; }
#pragma unroll
  for (int f = 0; f < 40; ++f) {
    const float* wrow = Wt + f * 8;
    const float vA = (float)curA[f >> 3][f & 7];
    const float vB = (float)curB[f >> 3][f & 7];
#pragma unroll
    for (int g = 0; g < 8; ++g) {
      const float w0 = wrow[g], w1 = wrow[1280 + g], w2 = wrow[2560 + g];
      accA[g] = fmaf(vA, fmaf(s2A, w2, fmaf(s1A, w1, w0)), accA[g]);
      accB[g] = fmaf(vB, fmaf(s2B, w2, fmaf(s1B, w1, w0)), accB[g]);
    }
  }
#pragma unroll
  for (int g = 0; g < 8; ++g) {
    accA[g] += __shfl_xor(accA[g], 16, 64);   // sum stat pairs
    accA[g] += __shfl_xor(accA[g], 32, 64);   // sum all 4 stats
    accB[g] += __shfl_xor(accB[g], 16, 64);
    accB[g] += __shfl_xor(accB[g], 32, 64);
  }
  if (s == 0) {
    const float* xpA = xpostT + t * (N_NODES * 8) + nA * 8;
    const float* xpB = xpA + 16 * 8;
#pragma unroll
    for (int g = 0; g < 8; ++g) {
      sP[ni * 41 + t * 8 + g] = accA[g] + xpA[g];
      sP[(ni + 16) * 41 + t * 8 + g] = accB[g] + xpB[g];
    }
  }
  __syncthreads();

  // ---- Phase B: W_lin mix (40x40) for 2 nodes + per-block stat partials
  const int cq = l & 3;
  const int nb = l >> 2;             // 0..15
  const int cc = t * 8 + cq * 2;
  float a0 = b_lin[cc], a1 = b_lin[cc + 1];
  float c0 = a0, c1 = a1;
  for (int k = 0; k < 40; ++k) {
    const float2 w = *(const float2*)(W_lin + k * EMB + cc);
    const float pA = sP[nb * 41 + k];
    const float pB = sP[(nb + 16) * 41 + k];
    a0 = fmaf(pA, w.x, a0);
    a1 = fmaf(pA, w.y, a1);
    c0 = fmaf(pB, w.x, c0);
    c1 = fmaf(pB, w.y, c1);
  }
  h0T[cc * N_NODES + n0 + nb] = a0;
  h0T[(cc + 1) * N_NODES + n0 + nb] = a1;
  h0T[cc * N_NODES + n0 + nb + 16] = c0;
  h0T[(cc + 1) * N_NODES + n0 + nb + 16] = c1;
  float sv0 = a0 + c0, sv1 = a1 + c1;
  float qv0 = a0 * a0 + c0 * c0, qv1 = a1 * a1 + c1 * c1;
#pragma unroll
  for (int m = 4; m <= 32; m <<= 1) {
    sv0 += __shfl_xor(sv0, m, 64);
    sv1 += __shfl_xor(sv1, m, 64);
    qv0 += __shfl_xor(qv0, m, 64);
    qv1 += __shfl_xor(qv1, m, 64);
  }
  if (nb == 0) {
    float* pb = partial + blockIdx.x * 80;
    pb[cc] = sv0;
    pb[cc + 1] = sv1;
    pb[40 + cc] = qv0;
    pb[40 + cc + 1] = qv1;
  }
}

// ---------------- K6: reduce partial[625][80] -> S1[40], S2[40] --------------
__global__ __launch_bounds__(256) void k_stats(const float* __restrict__ partial,
                                               float* __restrict__ S1,
                                               float* __restrict__ S2) {
  const int col = blockIdx.x;        // 0..79
  const int tid = threadIdx.x;
  __shared__ float red[4];
  float s = 0.f;
  for (int b = tid; b < NBLK_PM; b += 256) s += partial[b * 80 + col];
#pragma unroll
  for (int m = 32; m >= 1; m >>= 1) s += __shfl_xor(s, m, 64);
  if ((tid & 63) == 0) red[tid >> 6] = s;
  __syncthreads();
  if (tid == 0) {
    const float tot = (red[0] + red[1]) + (red[2] + red[3]);
    if (col < 40) S1[col] = tot;
    else S2[col - 40] = tot;
  }
}

// ---------------- K7: head; GN + MLP ----------------
__global__ __launch_bounds__(256) void k_head(const float* __restrict__ S1,
                                              const float* __restrict__ S2,
                                              const float* __restrict__ h0T,
                                              const float* __restrict__ gn_w,
                                              const float* __restrict__ gn_b,
                                              const float* __restrict__ gn_ms,
                                              const float* __restrict__ W1,
                                              const float* __restrict__ b1,
                                              const float* __restrict__ W2,
                                              const float* __restrict__ b2,
                                              float* __restrict__ out) {
  __shared__ float sV[64 * 41];
  __shared__ float sH[64 * 41];
  const int tid = threadIdx.x;
  const int n0 = blockIdx.x * 64;
  const float invN = 1.f / (float)N_NODES;
  for (int i = 0; i < 10; ++i) {
    const int idx = tid + i * 256;
    const int e = idx >> 6, r = idx & 63;
    const int nn0 = n0 + r;
    const int nn = (nn0 < N_NODES) ? nn0 : 0;
    const float M = S1[e] * invN;
    const float ms = gn_ms[e];
    const float var = S2[e] * invN - ms * (2.f - ms) * M * M;
    const float sc = gn_w[e] / sqrtf(var + 1e-5f);
    const float he = h0T[e * N_NODES + nn];       // coalesced (lane = node)
    sV[r * 41 + e] = fmaxf((he - ms * M) * sc + gn_b[e], 0.f);
  }
  __syncthreads();
  const int wv = tid >> 6, lane = tid & 63;
  const int c0 = wv * 10;
  float acc[10];
#pragma unroll
  for (int j = 0; j < 10; ++j) acc[j] = b1[c0 + j];
  for (int k = 0; k < 40; ++k) {
    const float p = sV[lane * 41 + k];
    const float* w = W1 + k * EMB + c0;           // wave-uniform -> scalar
#pragma unroll
    for (int j = 0; j < 10; ++j) acc[j] = fmaf(p, w[j], acc[j]);
  }
#pragma unroll
  for (int j = 0; j < 10; ++j) sH[lane * 41 + c0 + j] = fmaxf(acc[j], 0.f);
  __syncthreads();
  if (tid < 64) {
    const int n = n0 + tid;
    if (n < N_NODES) {
      float o0 = b2[0], o1 = b2[1];
      const float* hr = sH + tid * 41;
#pragma unroll
      for (int k = 0; k < 40; ++k) {
        const float r = hr[k];
        o0 = fmaf(r, W2[k * 2], o0);
        o1 = fmaf(r, W2[k * 2 + 1], o1);
      }
      out[n * 2] = o0;
      out[n * 2 + 1] = o1;
    }
  }
}

extern "C" void kernel_launch(void* const* d_in, const int* in_sizes, int n_in,
                              void* d_out, int out_size, void* d_ws, size_t ws_size,
                              hipStream_t stream) {
  const float* x      = (const float*)d_in[0];
  const int*   ei     = (const int*)d_in[1];
  const float* W_pre  = (const float*)d_in[2];
  const float* b_pre  = (const float*)d_in[3];
  const float* W_post = (const float*)d_in[4];
  const float* b_post = (const float*)d_in[5];
  const float* W_lin  = (const float*)d_in[6];
  const float* b_lin  = (const float*)d_in[7];
  const float* gn_w   = (const float*)d_in[8];
  const float* gn_b   = (const float*)d_in[9];
  const float* gn_ms  = (const float*)d_in[10];
  const float* W1     = (const float*)d_in[11];
  const float* b1     = (const float*)d_in[12];
  const float* W2     = (const float*)d_in[13];
  const float* b2     = (const float*)d_in[14];
  const float* avg_dl = (const float*)d_in[15];
  float* out = (float*)d_out;

  char* ws = (char*)d_ws;
  float* S1   = (float*)(ws + WS_STATS);
  float* S2   = S1 + 40;
  int* cursor = (int*)(ws + WS_CURSOR);
  int* ssrc   = (int*)(ws + WS_SSRC);
  _Float16* mS   = (_Float16*)(ws + WS_MS);
  _Float16* mD   = (_Float16*)(ws + WS_MD);
  _Float16* aggS = (_Float16*)(ws + WS_AGG);
  float* xpostT  = (float*)(ws + WS_XPOST);
  float* h0T     = (float*)(ws + WS_H0T);
  float* part    = (float*)(ws + WS_PART);
  const int* e_src = ei;
  const int* e_dst = ei + N_EDGES;

  k_pre<<<N_NODES / NPB_PRE, 256, 0, stream>>>(x, W_pre, b_pre, W_post, b_post,
                                               mS, mD, xpostT, cursor);
  k_scatter<<<(N_EDGES + 255) / 256, 256, 0, stream>>>(e_src, e_dst, cursor, ssrc);
  k_edge<<<N_NODES / 4, 256, 0, stream>>>(mS, mD, cursor, ssrc, aggS);
  k_postmix<<<NBLK_PM, 320, 0, stream>>>(aggS, cursor, W_post, avg_dl,
                                         xpostT, W_lin, b_lin, h0T, part);
  k_stats<<<80, 256, 0, stream>>>(part, S1, S2);
  k_head<<<NBLK_MIX, 256, 0, stream>>>(S1, S2, h0T, gn_w, gn_b, gn_ms,
                                       W1, b1, W2, b2, out);
}

// Round 4
// 191.693 us; speedup vs baseline: 1.2390x; 1.1640x over previous
//
#include <hip/hip_runtime.h>
#include <math.h>

#define N_NODES 20000
#define N_EDGES 320000
#define F_IN 40
#define T_TOW 5
#define EMB 40
#define NPB_PRE 16      // nodes per block in projection kernel -> 1250 blocks
#define NBLK_MIX 313    // ceil(20000/64) for k_head
#define NBLK_PM 313     // ceil(20000/64) for fused post+mix (64 nodes/block)
#define ECHUNK 16       // edge-loop software-pipeline depth
#define STRIDE 64       // fixed CSR bucket stride (Poisson(16) tail @64 ~ 1e-20)

typedef __attribute__((ext_vector_type(8))) _Float16 half8;
typedef __attribute__((ext_vector_type(2))) _Float16 half2_t;
typedef __attribute__((ext_vector_type(4))) float f32x4;

// workspace byte offsets (all 64B-aligned)
#define WS_STATS   0          // S1[40], S2[40] float (written by k_stats)
#define WS_CURSOR  320        // int[N]  init to 64n by k_pre, bumped by k_scatter
#define WS_SSRC    80384      // int[N*64] fixed-stride edge buckets (5.12 MB)
#define WS_MS      5200384    // half[N*200] src-projection
#define WS_MD      13200384   // half[N*200] dst-projection (+bias)
#define WS_AGG     21200384   // half[5][N][160] tower-major agg, k = stat*40+f (32 MB)
#define WS_XPOST   53200384   // float[5][N][8]  x-part of post (+b_post)
#define WS_H0T     69200384   // float[40][N]    h0 transposed
#define WS_PART    72400384   // float[NBLK_PM*80] per-block stat partials (100 KB)

// ---------------- K_pre: per-node projections + x-part of post + cursor init --
__global__ __launch_bounds__(256) void k_pre(const float* __restrict__ x,
                                             const float* __restrict__ W_pre,
                                             const float* __restrict__ b_pre,
                                             const float* __restrict__ W_post,
                                             const float* __restrict__ b_post,
                                             _Float16* __restrict__ mS,
                                             _Float16* __restrict__ mD,
                                             float* __restrict__ xpostT,
                                             int* __restrict__ cursor) {
  const int tid = threadIdx.x;
  const int n0 = blockIdx.x * NPB_PRE;
  if (tid < NPB_PRE) cursor[n0 + tid] = (n0 + tid) * STRIDE;  // bucket-CSR init
  const bool statlane = tid < 200;
  const int q = tid - 200;
  const bool xplane = (q >= 0 && q < 40);
  const int tc = statlane ? tid : 199;
  const int t = tc / 40, g = tc - t * 40;
  const int t2 = xplane ? q / 8 : 0, g2 = xplane ? q - (q / 8) * 8 : 0;
  float wA[40], wB[40];
  const float* Wt = W_pre + t * 3200;
#pragma unroll
  for (int j = 0; j < 40; ++j) {
    wA[j] = statlane ? Wt[j * 40 + g] : W_post[t2 * 4160 + j * 8 + g2];
    wB[j] = statlane ? Wt[(40 + j) * 40 + g] : 0.f;
  }
  const float bias = statlane ? b_pre[t * 40 + g] : b_post[t2 * 8 + g2];
  for (int ni = 0; ni < NPB_PRE; ++ni) {
    const int n = n0 + ni;
    const float* xr = x + n * F_IN;
    float aA = bias, aB = 0.f;
#pragma unroll
    for (int j = 0; j < 40; j += 4) {
      const float4 xv = *(const float4*)(xr + j);
      aA += xv.x * wA[j] + xv.y * wA[j + 1] + xv.z * wA[j + 2] + xv.w * wA[j + 3];
      aB += xv.x * wB[j] + xv.y * wB[j + 1] + xv.z * wB[j + 2] + xv.w * wB[j + 3];
    }
    if (statlane) {
      mD[n * 200 + tc] = (_Float16)aA;
      mS[n * 200 + tc] = (_Float16)aB;
    } else if (xplane) {
      xpostT[t2 * (N_NODES * 8) + n * 8 + g2] = aA;
    }
  }
}

// ---------------- K3: scatter edges into fixed-stride buckets ----------------
__global__ __launch_bounds__(256) void k_scatter(const int* __restrict__ src,
                                                 const int* __restrict__ dst,
                                                 int* __restrict__ cursor,
                                                 int* __restrict__ ssrc) {
  int i = blockIdx.x * 256 + threadIdx.x;
  if (i < N_EDGES) {
    int d = dst[i];
    int pos = atomicAdd(&cursor[d], 1);
    ssrc[pos] = src[i];
  }
}

// ---------------- K4: edge loop; one wave per node, packed-fp16 math ----------
// agg output layout: [t][N][4][40] halfs -> per node a contiguous 160-half row
// with k = stat*40 + f (stat order: mean, min, max, std).
__global__ __launch_bounds__(256) void k_edge(const _Float16* __restrict__ mS,
                                              const _Float16* __restrict__ mD,
                                              const int* __restrict__ cursor,
                                              const int* __restrict__ ssrc,
                                              _Float16* __restrict__ aggS) {
  const int lane = threadIdx.x & 63;
  const int wv = threadIdx.x >> 6;
  const int n = blockIdx.x * 4 + wv;             // one wave per node
  const int r0 = n * STRIDE;                     // scalar
  const int r1 = __builtin_amdgcn_readfirstlane(cursor[n]);
  const int cnt = r1 - r0;
  const int cpa = lane;                          // cols 2l, 2l+1
  const bool bact = lane < 36;                   // cp 64..99 -> cols 128..199
  const int cpb = bact ? 64 + lane : 99;
  const half2_t mda = ((const half2_t*)(mD + n * 200))[cpa];
  const half2_t mdb = ((const half2_t*)(mD + n * 200))[cpb];

  const _Float16 HINF = (_Float16)65504.f;
  half2_t suma = {0, 0}, ssqa = {0, 0}, sumb = {0, 0}, ssqb = {0, 0};
  half2_t mna = {HINF, HINF}, mxa = {-HINF, -HINF};
  half2_t mnb = {HINF, HINF}, mxb = {-HINF, -HINF};
  half2_t va = {0, 0}, vb = {0, 0};

  if (cnt > 0) {
    for (int p = r0; p < r1; p += ECHUNK) {
      half2_t ha[ECHUNK], hb[ECHUNK];
#pragma unroll
      for (int i = 0; i < ECHUNK; ++i) {
        const int qe = (p + i < r1) ? (p + i) : (r1 - 1);   // s_cselect
        const int s = __builtin_amdgcn_readfirstlane(ssrc[qe]);
        const half2_t* row = (const half2_t*)(mS + s * 200);
        ha[i] = row[cpa];
        hb[i] = row[cpb];
      }
#pragma unroll
      for (int i = 0; i < ECHUNK; ++i) {
        suma += ha[i];
        ssqa += ha[i] * ha[i];
        mna = __builtin_elementwise_min(mna, ha[i]);
        mxa = __builtin_elementwise_max(mxa, ha[i]);
        sumb += hb[i];
        ssqb += hb[i] * hb[i];
        mnb = __builtin_elementwise_min(mnb, hb[i]);
        mxb = __builtin_elementwise_max(mxb, hb[i]);
      }
      va = ha[ECHUNK - 1];
      vb = hb[ECHUNK - 1];
    }
  }

  const int padded = ((cnt + ECHUNK - 1) / ECHUNK) * ECHUNK;
  const float d = (float)(padded - cnt);
  const float inv = (cnt > 0) ? 1.f / (float)cnt : 0.f;
#pragma unroll
  for (int set = 0; set < 2; ++set) {
    if (set == 1 && !bact) break;
    const int cp = set == 0 ? cpa : cpb;
    const half2_t sum2 = set == 0 ? suma : sumb;
    const half2_t ssq2 = set == 0 ? ssqa : ssqb;
    const half2_t mn2 = set == 0 ? mna : mnb;
    const half2_t mx2 = set == 0 ? mxa : mxb;
    const half2_t vl2 = set == 0 ? va : vb;
    const half2_t md2 = set == 0 ? mda : mdb;
    half2_t omean, omn, omx, osd;
#pragma unroll
    for (int j = 0; j < 2; ++j) {
      float mean, mnf, mxf, sd;
      if (cnt > 0) {
        const float vl = (float)vl2[j];
        const float sf = (float)sum2[j] - d * vl;
        const float qf = (float)ssq2[j] - d * vl * vl;
        const float msm = sf * inv;
        const float var = qf * inv - msm * msm;
        sd = sqrtf(fmaxf(var, 0.f) + 1e-5f);
        const float mdf = (float)md2[j];
        mean = mdf + msm;
        mnf = mdf + (float)mn2[j];
        mxf = mdf + (float)mx2[j];
      } else {
        mean = 0.f; mnf = 0.f; mxf = 0.f; sd = sqrtf(1e-5f);
      }
      omean[j] = (_Float16)mean;
      omn[j] = (_Float16)mnf;
      omx[j] = (_Float16)mxf;
      osd[j] = (_Float16)sd;
    }
    const int t = cp / 20, g = 2 * (cp - t * 20);
    _Float16* abase = aggS + ((size_t)t * N_NODES + n) * 160 + g;
    *(half2_t*)(abase) = omean;          // mean  (k = 0..39)
    *(half2_t*)(abase + 40) = omn;       // min   (k = 40..79)
    *(half2_t*)(abase + 80) = omx;       // max   (k = 80..119)
    *(half2_t*)(abase + 120) = osd;      // std   (k = 120..159)
  }
}

// ---------------- K5: fused post-MLP (MFMA) + W_lin mix ----------------------
// 313 blocks x 320 threads, 64 nodes/block, wave = tower t.
// Phase A: per-tower GEMM [64,160] x [160,24] via mfma_f32_16x16x32_f16.
//   Scalers factor out: out = A + s1[n]*B + s2[n]*C where A/B/C share the agg
//   input. B-frags built once/wave: Wc1 = [w0|w1] (cols 0..15), Wc2 = [w2|0].
//   D layout (verified): col = lane&15, row = (lane>>4)*4 + reg.
// Phase B: wave t owns cols t*8..t*8+7, lane = node; 40-step W_lin mix +
//   per-block stat partials via shfl tree.
__global__ __launch_bounds__(320) void k_postmix(const _Float16* __restrict__ aggT,
                                                 const int* __restrict__ cursor,
                                                 const float* __restrict__ W_post,
                                                 const float* __restrict__ avg_dl,
                                                 const float* __restrict__ xpostT,
                                                 const float* __restrict__ W_lin,
                                                 const float* __restrict__ b_lin,
                                                 float* __restrict__ h0T,
                                                 float* __restrict__ partial) {
  __shared__ float sP[64 * 41];
  const int tid = threadIdx.x;
  const int t = tid >> 6;            // tower (wave-uniform)
  const int l = tid & 63;
  const int n0 = blockIdx.x * 64;
  const int c = l & 15;              // A row within tile / D col
  const int kg = l >> 4;             // k-group 0..3

  // ---- build B fragments once per wave (L2-hot after first blocks)
  const float* Wt = W_post + t * 4160;
  half8 b1f[5], b2f[5];
#pragma unroll
  for (int ks = 0; ks < 5; ++ks) {
#pragma unroll
    for (int j = 0; j < 8; ++j) {
      const int k = ks * 32 + kg * 8 + j;
      const float w1v = (c < 8) ? Wt[(40 + k) * 8 + c] : Wt[(200 + k) * 8 + (c - 8)];
      const float w2v = (c < 8) ? Wt[(360 + k) * 8 + c] : 0.f;
      b1f[ks][j] = (_Float16)w1v;
      b2f[ks][j] = (_Float16)w2v;
    }
  }
  const float avg = avg_dl[0];

  // ---- Phase A: 4 tiles of 16 nodes
  for (int tile = 0; tile < 4; ++tile) {
    const int nb = n0 + tile * 16;
    int nA = nb + c;
    if (nA >= N_NODES) nA = N_NODES - 1;
    const half8* ar = (const half8*)(aggT + ((size_t)t * N_NODES + nA) * 160);
    half8 af[5];
#pragma unroll
    for (int ks = 0; ks < 5; ++ks) af[ks] = ar[ks * 4 + kg];
    f32x4 acc1 = {0.f, 0.f, 0.f, 0.f}, acc2 = {0.f, 0.f, 0.f, 0.f};
#pragma unroll
    for (int ks = 0; ks < 5; ++ks) {
      acc1 = __builtin_amdgcn_mfma_f32_16x16x32_f16(af[ks], b1f[ks], acc1, 0, 0, 0);
      acc2 = __builtin_amdgcn_mfma_f32_16x16x32_f16(af[ks], b2f[ks], acc2, 0, 0, 0);
    }
    // lanes c and c^8 share the same rows -> pull B-part (w1) into c<8 lanes
    float bp[4];
#pragma unroll
    for (int r = 0; r < 4; ++r) bp[r] = __shfl_xor(acc1[r], 8, 64);
    if (c < 8) {
#pragma unroll
      for (int r = 0; r < 4; ++r) {
        const int nn0 = nb + kg * 4 + r;
        const int nn = (nn0 < N_NODES) ? nn0 : N_NODES - 1;
        const int cnt = cursor[nn] - nn * STRIDE;
        const float ld = logf(fmaxf((float)cnt, 1.f) + 1.f);
        const float s1 = ld / avg, s2 = avg / ld;
        const float xp = xpostT[t * (N_NODES * 8) + nn * 8 + c];
        sP[(tile * 16 + kg * 4 + r) * 41 + t * 8 + c] =
            acc1[r] + s1 * bp[r] + s2 * acc2[r] + xp;
      }
    }
  }
  __syncthreads();

  // ---- Phase B: W_lin mix (40x40) + per-block stat partials
  const int c0 = t * 8;
  float acc[8];
#pragma unroll
  for (int j = 0; j < 8; ++j) acc[j] = b_lin[c0 + j];
  for (int k = 0; k < 40; ++k) {
    const float p = sP[l * 41 + k];
    const float* w = W_lin + k * EMB + c0;        // wave-uniform -> scalar
#pragma unroll
    for (int j = 0; j < 8; ++j) acc[j] = fmaf(p, w[j], acc[j]);
  }
  const int n = n0 + l;
  const bool ok = n < N_NODES;
  if (ok) {
#pragma unroll
    for (int j = 0; j < 8; ++j) h0T[(c0 + j) * N_NODES + n] = acc[j];
  }
#pragma unroll
  for (int j = 0; j < 8; ++j) {
    float sv = ok ? acc[j] : 0.f;
    float qv = sv * sv;
#pragma unroll
    for (int m = 32; m >= 1; m >>= 1) {
      sv += __shfl_xor(sv, m, 64);
      qv += __shfl_xor(qv, m, 64);
    }
    if (l == 0) {
      partial[blockIdx.x * 80 + c0 + j] = sv;
      partial[blockIdx.x * 80 + 40 + c0 + j] = qv;
    }
  }
}

// ---------------- K6: reduce partial[313][80] -> S1[40], S2[40] --------------
__global__ __launch_bounds__(256) void k_stats(const float* __restrict__ partial,
                                               float* __restrict__ S1,
                                               float* __restrict__ S2) {
  const int col = blockIdx.x;        // 0..79
  const int tid = threadIdx.x;
  __shared__ float red[4];
  float s = 0.f;
  for (int b = tid; b < NBLK_PM; b += 256) s += partial[b * 80 + col];
#pragma unroll
  for (int m = 32; m >= 1; m >>= 1) s += __shfl_xor(s, m, 64);
  if ((tid & 63) == 0) red[tid >> 6] = s;
  __syncthreads();
  if (tid == 0) {
    const float tot = (red[0] + red[1]) + (red[2] + red[3]);
    if (col < 40) S1[col] = tot;
    else S2[col - 40] = tot;
  }
}

// ---------------- K7: head; GN + MLP ----------------
__global__ __launch_bounds__(256) void k_head(const float* __restrict__ S1,
                                              const float* __restrict__ S2,
                                              const float* __restrict__ h0T,
                                              const float* __restrict__ gn_w,
                                              const float* __restrict__ gn_b,
                                              const float* __restrict__ gn_ms,
                                              const float* __restrict__ W1,
                                              const float* __restrict__ b1,
                                              const float* __restrict__ W2,
                                              const float* __restrict__ b2,
                                              float* __restrict__ out) {
  __shared__ float sV[64 * 41];
  __shared__ float sH[64 * 41];
  const int tid = threadIdx.x;
  const int n0 = blockIdx.x * 64;
  const float invN = 1.f / (float)N_NODES;
  for (int i = 0; i < 10; ++i) {
    const int idx = tid + i * 256;
    const int e = idx >> 6, r = idx & 63;
    const int nn0 = n0 + r;
    const int nn = (nn0 < N_NODES) ? nn0 : 0;
    const float M = S1[e] * invN;
    const float ms = gn_ms[e];
    const float var = S2[e] * invN - ms * (2.f - ms) * M * M;
    const float sc = gn_w[e] / sqrtf(var + 1e-5f);
    const float he = h0T[e * N_NODES + nn];       // coalesced (lane = node)
    sV[r * 41 + e] = fmaxf((he - ms * M) * sc + gn_b[e], 0.f);
  }
  __syncthreads();
  const int wv = tid >> 6, lane = tid & 63;
  const int c0 = wv * 10;
  float acc[10];
#pragma unroll
  for (int j = 0; j < 10; ++j) acc[j] = b1[c0 + j];
  for (int k = 0; k < 40; ++k) {
    const float p = sV[lane * 41 + k];
    const float* w = W1 + k * EMB + c0;           // wave-uniform -> scalar
#pragma unroll
    for (int j = 0; j < 10; ++j) acc[j] = fmaf(p, w[j], acc[j]);
  }
#pragma unroll
  for (int j = 0; j < 10; ++j) sH[lane * 41 + c0 + j] = fmaxf(acc[j], 0.f);
  __syncthreads();
  if (tid < 64) {
    const int n = n0 + tid;
    if (n < N_NODES) {
      float o0 = b2[0], o1 = b2[1];
      const float* hr = sH + tid * 41;
#pragma unroll
      for (int k = 0; k < 40; ++k) {
        const float r = hr[k];
        o0 = fmaf(r, W2[k * 2], o0);
        o1 = fmaf(r, W2[k * 2 + 1], o1);
      }
      out[n * 2] = o0;
      out[n * 2 + 1] = o1;
    }
  }
}

extern "C" void kernel_launch(void* const* d_in, const int* in_sizes, int n_in,
                              void* d_out, int out_size, void* d_ws, size_t ws_size,
                              hipStream_t stream) {
  const float* x      = (const float*)d_in[0];
  const int*   ei     = (const int*)d_in[1];
  const float* W_pre  = (const float*)d_in[2];
  const float* b_pre  = (const float*)d_in[3];
  const float* W_post = (const float*)d_in[4];
  const float* b_post = (const float*)d_in[5];
  const float* W_lin  = (const float*)d_in[6];
  const float* b_lin  = (const float*)d_in[7];
  const float* gn_w   = (const float*)d_in[8];
  const float* gn_b   = (const float*)d_in[9];
  const float* gn_ms  = (const float*)d_in[10];
  const float* W1     = (const float*)d_in[11];
  const float* b1     = (const float*)d_in[12];
  const float* W2     = (const float*)d_in[13];
  const float* b2     = (const float*)d_in[14];
  const float* avg_dl = (const float*)d_in[15];
  float* out = (float*)d_out;

  char* ws = (char*)d_ws;
  float* S1   = (float*)(ws + WS_STATS);
  float* S2   = S1 + 40;
  int* cursor = (int*)(ws + WS_CURSOR);
  int* ssrc   = (int*)(ws + WS_SSRC);
  _Float16* mS   = (_Float16*)(ws + WS_MS);
  _Float16* mD   = (_Float16*)(ws + WS_MD);
  _Float16* aggS = (_Float16*)(ws + WS_AGG);
  float* xpostT  = (float*)(ws + WS_XPOST);
  float* h0T     = (float*)(ws + WS_H0T);
  float* part    = (float*)(ws + WS_PART);
  const int* e_src = ei;
  const int* e_dst = ei + N_EDGES;

  k_pre<<<N_NODES / NPB_PRE, 256, 0, stream>>>(x, W_pre, b_pre, W_post, b_post,
                                               mS, mD, xpostT, cursor);
  k_scatter<<<(N_EDGES + 255) / 256, 256, 0, stream>>>(e_src, e_dst, cursor, ssrc);
  k_edge<<<N_NODES / 4, 256, 0, stream>>>(mS, mD, cursor, ssrc, aggS);
  k_postmix<<<NBLK_PM, 320, 0, stream>>>(aggS, cursor, W_post, avg_dl,
                                         xpostT, W_lin, b_lin, h0T, part);
  k_stats<<<80, 256, 0, stream>>>(part, S1, S2);
  k_head<<<NBLK_MIX, 256, 0, stream>>>(S1, S2, h0T, gn_w, gn_b, gn_ms,
                                       W1, b1, W2, b2, out);
}